// Round 3
// 196.470 us; speedup vs baseline: 1.0494x; 1.0494x over previous
//
#include <hip/hip_runtime.h>
#include <hip/hip_bf16.h>
#include <stdint.h>

// Problem constants (fixed-shape problem)
#define HEADS 16
#define HDIM  64
#define DIMC  1024
#define INNER 1024
#define LSEQ  2048
#define BLM   4096   // B*L

typedef unsigned short u16;
typedef __attribute__((ext_vector_type(8))) short bf16x8;  // 8 bf16 = 4 VGPRs
typedef __attribute__((ext_vector_type(4))) float f32x4;

__device__ __forceinline__ u16 f2bf(float f) {
  union { float f; uint32_t u; } v; v.f = f;
  uint32_t u = v.u;
  return (u16)((u + 0x7fffu + ((u >> 16) & 1u)) >> 16);  // RNE
}
__device__ __forceinline__ uint32_t pack_bf2(float a, float b) {
  float2 f2; f2.x = a; f2.y = b;
  __hip_bfloat162 t = __float22bfloat162_rn(f2);
  union { __hip_bfloat162 h; uint32_t u; } c; c.h = t; return c.u;
}
// raw quarter-rate HW exp2 — avoids OCML's precise-path polynomial
__device__ __forceinline__ float fast_exp2(float x) {
  float r; asm("v_exp_f32 %0, %1" : "=v"(r) : "v"(x)); return r;
}

// async global->LDS, 16B per lane; LDS dest = wave-uniform base + lane*16
__device__ __forceinline__ void load_lds16(const void* g, void* l) {
  __builtin_amdgcn_global_load_lds(
      (const __attribute__((address_space(1))) uint32_t*)g,
      (__attribute__((address_space(3))) uint32_t*)l, 16, 0, 0);
}

// --------------------------------------------------- fused prep (1 launch):
// blocks [0,4096): cast x f32->bf16
// blocks [4096,7168): transpose+cast w_qkv [1024][3072] -> [3072][1024]
// NOTE: w_out transpose is NOT fused here. woutT aliases wqkvT's ws region
// and may only be written AFTER gemm1 has consumed wqkvT — writing it in
// prep clobbered the Q-columns of wqkvT (the R9/R11 absmax-0.316 bug).
__global__ __launch_bounds__(256) void prep_k(const float* __restrict__ x,
                                              const float* __restrict__ w_qkv,
                                              u16* __restrict__ xb,
                                              u16* __restrict__ wqkvT) {
  __shared__ float tile[32][33];
  int bid = blockIdx.x;
  if (bid < 4096) {
    int i = (bid * 256 + threadIdx.x) * 4;
    float4 v = *(const float4*)(x + i);
    ushort4 o;
    o.x = f2bf(v.x); o.y = f2bf(v.y); o.z = f2bf(v.z); o.w = f2bf(v.w);
    *(ushort4*)(xb + i) = o;
    return;
  }
  int idx = bid - 4096;
  int bx = idx % 96, by = idx / 96;   // C=3072 -> 96 col-tiles, R=1024 -> 32 row-tiles
  int c0 = bx * 32, r0 = by * 32;
  int j = threadIdx.x & 31, i0 = threadIdx.x >> 5;
#pragma unroll
  for (int p = 0; p < 4; ++p) {
    int i = i0 + p * 8;
    tile[i][j] = w_qkv[(size_t)(r0 + i) * 3072 + (c0 + j)];
  }
  __syncthreads();
#pragma unroll
  for (int p = 0; p < 4; ++p) {
    int i = i0 + p * 8;
    wqkvT[(size_t)(c0 + i) * 1024 + (r0 + j)] = f2bf(tile[j][i]);
  }
}

// ------------------------------------------------- transpose+cast: [R][C]f32 -> [C][R]bf16
__global__ __launch_bounds__(256) void transpose_cast_k(const float* __restrict__ in,
                                                        u16* __restrict__ out,
                                                        int R, int C) {
  __shared__ float tile[32][33];
  int c0 = blockIdx.x * 32, r0 = blockIdx.y * 32;
  int j = threadIdx.x & 31, i0 = threadIdx.x >> 5;
#pragma unroll
  for (int p = 0; p < 4; ++p) {
    int i = i0 + p * 8;
    tile[i][j] = in[(size_t)(r0 + i) * C + (c0 + j)];
  }
  __syncthreads();
#pragma unroll
  for (int p = 0; p < 4; ++p) {
    int i = i0 + p * 8;
    out[(size_t)(c0 + i) * R + (r0 + j)] = f2bf(tile[j][i]);
  }
}

// ------------------------------------------------------------------ GEMM (B^T input)
// C[M][N] = A[M][K] @ Bt[N][K], bf16 in, fp32 accum. TMx128 tile, BK=64.
// EPI==1: store f32 (acc + bias[col] + resid[row][col]).
// EPI==2: QKV split: cols<2048 -> Cb (stride 2048, Q|K packed);
//         cols>=2048 are V -> transposed store into Vt[bh][d][l].
template <int EPI, int TM>
__global__ __launch_bounds__(256) void gemm_bt(const u16* __restrict__ A,
                                               const u16* __restrict__ Bt,
                                               u16* __restrict__ Cb,
                                               float* __restrict__ Cf,
                                               const float* __restrict__ bias,
                                               const float* __restrict__ resid,
                                               u16* __restrict__ Vt,
                                               int M, int N, int K) {
  constexpr int MI = TM / 32;  // A-frags per wave (wave m-extent = TM/2)
  __shared__ alignas(16) u16 As[TM * 64];
  __shared__ alignas(16) u16 Bs[128 * 64];
  const int tid = threadIdx.x;
  const int lane = tid & 63;
  const int w = tid >> 6;
  const int wm = w >> 1, wn = w & 1;
  const int m0 = blockIdx.y * TM, n0 = blockIdx.x * 128;
  const int ln = lane & 15, qq = lane >> 4;
  const f32x4 zero4 = {0.f, 0.f, 0.f, 0.f};

  f32x4 acc[MI][4];
#pragma unroll
  for (int i = 0; i < MI; ++i)
#pragma unroll
    for (int j = 0; j < 4; ++j) acc[i][j] = zero4;

  for (int kt = 0; kt < K; kt += 64) {
    __syncthreads();
    // rows of 64 bf16 = 8 chunks of 16B; dest chunk d holds global chunk
    // d ^ (r&7) so frag reads (chunk (ks*4+qq)^(r&7)) spread all banks.
#pragma unroll
    for (int p = 0; p < TM / 32; ++p) {
      int t = p * 256 + tid;
      int r = t >> 3;
      int cl = (t & 7) ^ (r & 7);
      load_lds16(A + (size_t)(m0 + r) * K + kt + cl * 8,
                 (char*)As + (p * 256 + w * 64) * 16);
    }
#pragma unroll
    for (int p = 0; p < 4; ++p) {
      int t = p * 256 + tid;
      int r = t >> 3;
      int cl = (t & 7) ^ (r & 7);
      load_lds16(Bt + (size_t)(n0 + r) * K + kt + cl * 8,
                 (char*)Bs + (p * 256 + w * 64) * 16);
    }
    __syncthreads();
#pragma unroll
    for (int ks = 0; ks < 2; ++ks) {
      bf16x8 af[MI], bfr[4];
#pragma unroll
      for (int i = 0; i < MI; ++i) {
        int ra = wm * (TM / 2) + i * 16 + ln;
        af[i] = *(const bf16x8*)(As + (ra * 8 + ((ks * 4 + qq) ^ (ra & 7))) * 8);
      }
#pragma unroll
      for (int j = 0; j < 4; ++j) {
        int rb = wn * 64 + j * 16 + ln;
        bfr[j] = *(const bf16x8*)(Bs + (rb * 8 + ((ks * 4 + qq) ^ (rb & 7))) * 8);
      }
#pragma unroll
      for (int i = 0; i < MI; ++i)
#pragma unroll
        for (int j = 0; j < 4; ++j)
          acc[i][j] = __builtin_amdgcn_mfma_f32_16x16x32_bf16(af[i], bfr[j],
                                                              acc[i][j], 0, 0, 0);
    }
  }

  // C/D layout (m89-verified): col = lane&15, row = (lane>>4)*4 + reg
#pragma unroll
  for (int i = 0; i < MI; ++i) {
#pragma unroll
    for (int j = 0; j < 4; ++j) {
      int col = n0 + wn * 64 + j * 16 + ln;
      if (EPI == 1) {
#pragma unroll
        for (int rr = 0; rr < 4; ++rr) {
          int row = m0 + wm * (TM / 2) + i * 16 + qq * 4 + rr;
          Cf[(size_t)row * N + col] =
              acc[i][j][rr] + bias[col] + resid[(size_t)row * N + col];
        }
      } else {  // EPI == 2
        if (col < 2048) {
#pragma unroll
          for (int rr = 0; rr < 4; ++rr) {
            int row = m0 + wm * (TM / 2) + i * 16 + qq * 4 + rr;
            Cb[(size_t)row * 2048 + col] = f2bf(acc[i][j][rr]);
          }
        } else {
          // V column: store transposed Vt[(b*16+h)*64+d][l], 4 consecutive l
          int dg = col - 2048;
          int hh = dg >> 6, dd = dg & 63;
          int l0 = (m0 & 2047) + wm * (TM / 2) + i * 16 + qq * 4;
          int bb = m0 >> 11;
          ushort4 pk;
          pk.x = f2bf(acc[i][j][0]); pk.y = f2bf(acc[i][j][1]);
          pk.z = f2bf(acc[i][j][2]); pk.w = f2bf(acc[i][j][3]);
          *(ushort4*)(Vt + (((size_t)bb * 16 + hh) * 64 + dd) * 2048 + l0) = pk;
        }
      }
    }
  }
}

// ------------------------------------------------------------------ flash attention (S^T form)
// R15: square per-wave tiles (2 key-half x 2 q-half waves, 32x32 S^T each)
// -> K/V re-read factor 4->2; LDS reads 18->10 ds_read_b128/wave-iter.
// P round-trips through a compact per-wave LDS buffer [32q][32k] (R12's
// validated pattern re-derived for 32-key rows: 16B-unit swizzle
// u^((ln>>1)&3), collision-free, bijective per row).
// Schedule (spill-proof, fixes R14's absmax-0.125 stale-LDS bug): issue
// next-tile DMA at iter top, compute on cur, then vmcnt(0) + ONE raw
// s_barrier at iter bottom. vmcnt(0) counts scratch traffic too, so no
// counted-vmcnt miscount is possible; DMA flies under the whole compute
// phase so the drain bubble is small. No __launch_bounds__ reg cap (R14's
// (256,4) forced spills whose scratch ops broke the vmcnt(4) count).
__global__ __launch_bounds__(256) void attn_fused(const u16* __restrict__ qk,
                                                  const u16* __restrict__ vt,
                                                  u16* __restrict__ outp) {
  const int bh = blockIdx.x & 31;   // b*16+h  -> XCD group = bh%8 (R10 remap)
  const int qt = blockIdx.x >> 5;
  const int h = bh & 15;
  const int b = bh >> 4;
  const int tid = threadIdx.x;
  const int lane = tid & 63;
  const int w = tid >> 6;
  const int wq = w & 1;    // q-half   (32 q rows)
  const int wk = w >> 1;   // key-half (32 keys)
  const int ln = lane & 15, q4 = lane >> 4;
  const int l7 = ln & 7;
  const int swz = (ln >> 1) & 3;   // per-row P swizzle constant
  const f32x4 zero4 = {0.f, 0.f, 0.f, 0.f};

  // [0,16K): K double-buffer [2][64key][64d]  (chunk-swizzled c^(row&7))
  // [16K,32K): V^T double-buffer [2][64d][64key]
  // [32K,40K): per-wave P buffer [4][32q][32k], 16B-unit swizzle u^((ln>>1)&3)
  // epilogue reuses [0,27K): osc f32[2][32][68] | lsb f32[2][2][32] | obuf u16[2][32][72]
  __shared__ alignas(16) char smem[40960];
  u16* Ksb = (u16*)smem;
  u16* Vsb = (u16*)(smem + 16384);
  u16* Psw = (u16*)(smem + 32768);

  const size_t bh_tok = (size_t)b * LSEQ;
  const size_t vbase = ((size_t)b * 16 + h) * 64 * 2048;
  const int baseQ = h * HDIM;

  // ---- Q raw loads FIRST (their wait cannot stall the staging DMA)
  bf16x8 qraw[2][2];
#pragma unroll
  for (int nt = 0; nt < 2; ++nt) {
    int row = qt * 64 + wq * 32 + nt * 16 + ln;
    const u16* p = qk + (bh_tok + row) * 2048 + baseQ;
#pragma unroll
    for (int ks = 0; ks < 2; ++ks)
      qraw[nt][ks] = *(const bf16x8*)(p + q4 * 8 + 32 * ks);
  }

  // ---- stage tile 0 into buf 0 (4 global_load_lds per lane)
#pragma unroll
  for (int iss = 0; iss < 2; ++iss) {
    int idx = iss * 256 + tid;
    int row = idx >> 3, c = idx & 7;
    int cl = c ^ (row & 7);
    load_lds16(qk + (bh_tok + row) * 2048 + 1024 + baseQ + cl * 8,
               (char*)Ksb + (iss * 256 + w * 64) * 16);
    load_lds16(vt + vbase + (size_t)row * 2048 + cl * 8,
               (char*)Vsb + (iss * 256 + w * 64) * 16);
  }

  // ---- Q fragments (B-operand: n=ln, k=q4*8+j (+32*ks)), scaled by log2e/8
  const float qscale = 0.125f * 1.44269504088896340736f;
  bf16x8 qf[2][2];  // [nt][ks]
#pragma unroll
  for (int nt = 0; nt < 2; ++nt)
#pragma unroll
    for (int ks = 0; ks < 2; ++ks) {
      bf16x8 v = qraw[nt][ks];
      bf16x8 o;
#pragma unroll
      for (int jj = 0; jj < 8; ++jj) {
        union { uint32_t u; float f; } cv; cv.u = ((uint32_t)(u16)v[jj]) << 16;
        o[jj] = (short)f2bf(cv.f * qscale);
      }
      qf[nt][ks] = o;
    }

  float lsum[2] = {0.f, 0.f};  // per-lane partial row sums, per nt (q=16nt+ln)
  f32x4 o_acc[4][2];           // O^T partial: [dt: d=16dt+4q4+r][nt: q=16nt+ln]
#pragma unroll
  for (int dt = 0; dt < 4; ++dt) {
    o_acc[dt][0] = zero4;
    o_acc[dt][1] = zero4;
  }

  u16* pw = Psw + w * 1024;  // this wave's P buffer (32x32 bf16, 2 KB)

  // tile 0 landed everywhere before anyone computes
  asm volatile("s_waitcnt vmcnt(0)" ::: "memory");
  __builtin_amdgcn_s_barrier();

  int cur = 0;
#pragma unroll 1
  for (int jt = 0; jt < 32; ++jt) {
    // issue prefetch of tile jt+1 into buf cur^1; DMA flies under compute
    if (jt < 31) {
      const int key0 = (jt + 1) * 64;
#pragma unroll
      for (int iss = 0; iss < 2; ++iss) {
        int idx = iss * 256 + tid;
        int row = idx >> 3, c = idx & 7;
        int cl = c ^ (row & 7);
        load_lds16(qk + (bh_tok + key0 + row) * 2048 + 1024 + baseQ + cl * 8,
                   (char*)Ksb + (cur ^ 1) * 8192 + (iss * 256 + w * 64) * 16);
        load_lds16(vt + vbase + (size_t)row * 2048 + key0 + cl * 8,
                   (char*)Vsb + (cur ^ 1) * 8192 + (iss * 256 + w * 64) * 16);
      }
    }

    const u16* Ks = Ksb + cur * 4096;
    const u16* Vs = Vsb + cur * 4096;

    // S^T[32key][32q] = K·Q^T : 2 kt x 2 nt, 2 ks over d (4 K-frag reads)
    f32x4 s_[2][2];
#pragma unroll
    for (int kt = 0; kt < 2; ++kt) { s_[kt][0] = zero4; s_[kt][1] = zero4; }
#pragma unroll
    for (int kt = 0; kt < 2; ++kt) {
      int row = wk * 32 + kt * 16 + ln;
#pragma unroll
      for (int ks = 0; ks < 2; ++ks) {
        bf16x8 kf = *(const bf16x8*)(Ks + (row * 8 + ((ks * 4 + q4) ^ l7)) * 8);
        s_[kt][0] = __builtin_amdgcn_mfma_f32_16x16x32_bf16(kf, qf[0][ks], s_[kt][0], 0, 0, 0);
        s_[kt][1] = __builtin_amdgcn_mfma_f32_16x16x32_bf16(kf, qf[1][ks], s_[kt][1], 0, 0, 0);
      }
    }

    // static softmax: P = 2^S, accumulate per-lane per-nt partial sums
#pragma unroll
    for (int kt = 0; kt < 2; ++kt)
#pragma unroll
      for (int nt = 0; nt < 2; ++nt)
#pragma unroll
        for (int r = 0; r < 4; ++r) {
          float p = fast_exp2(s_[kt][nt][r]);
          s_[kt][nt][r] = p;
          lsum[nt] += p;
        }

    // P^T (C-layout: lane holds keys kt*16+q4*4+{0..3} at q=nt*16+ln) ->
    // per-wave LDS [q][32k]; logical 16B-unit u = 2kt+(q4>>1), half q4&1,
    // stored at u ^ swz (swz = (ln>>1)&3 = row swizzle constant).
#pragma unroll
    for (int kt = 0; kt < 2; ++kt)
#pragma unroll
      for (int nt = 0; nt < 2; ++nt) {
        uint2 pd;
        pd.x = pack_bf2(s_[kt][nt][0], s_[kt][nt][1]);
        pd.y = pack_bf2(s_[kt][nt][2], s_[kt][nt][3]);
        int u = (2 * kt + (q4 >> 1)) ^ swz;
        *(uint2*)(pw + (nt * 16 + ln) * 32 + u * 8 + (q4 & 1) * 4) = pd;
      }
    asm volatile("s_waitcnt lgkmcnt(0)" ::: "memory");  // wave-local W->R fence

    // B-frag read: lane needs keys q4*8..q4*8+7 at q=nt*16+ln -> unit q4^swz
    bf16x8 pfrag[2];
#pragma unroll
    for (int nt = 0; nt < 2; ++nt)
      pfrag[nt] = *(const bf16x8*)(pw + (nt * 16 + ln) * 32 + ((q4 ^ swz) * 8));

    // O^T[64d][32q] += V^T[d][wk-keys] · P^T[wk-keys][q]  (4 V-frag reads, k=32)
#pragma unroll
    for (int dt = 0; dt < 4; ++dt) {
      int row = dt * 16 + ln;
      bf16x8 va = *(const bf16x8*)(Vs + (row * 8 + ((wk * 4 + q4) ^ l7)) * 8);
      o_acc[dt][0] = __builtin_amdgcn_mfma_f32_16x16x32_bf16(va, pfrag[0], o_acc[dt][0], 0, 0, 0);
      o_acc[dt][1] = __builtin_amdgcn_mfma_f32_16x16x32_bf16(va, pfrag[1], o_acc[dt][1], 0, 0, 0);
    }

    // drain prefetch DMA (counts ALL vmem incl. any scratch -> spill-proof),
    // then one barrier: all waves done reading cur AND tile jt+1 landed.
    asm volatile("s_waitcnt vmcnt(0)" ::: "memory");
    __builtin_amdgcn_s_barrier();
    cur ^= 1;
  }

  // ---- epilogue: reduce lsum over lane groups (keys of this wave's half)
#pragma unroll
  for (int nt = 0; nt < 2; ++nt) {
    lsum[nt] += __shfl_xor(lsum[nt], 16);
    lsum[nt] += __shfl_xor(lsum[nt], 32);
  }

  float* osc = (float*)smem;              // [wq][32 q][68] f32 (17408 B)
  float* lsb = (float*)(smem + 17408);    // [wq][wk][32 q]   (512 B)
  u16* obuf = (u16*)(smem + 17920);       // [wq][32 q][72] u16 (9216 B)

  if (q4 == 0) {
    lsb[(wq * 2 + wk) * 32 + ln] = lsum[0];
    lsb[(wq * 2 + wk) * 32 + 16 + ln] = lsum[1];
  }
  if (wk == 1) {
#pragma unroll
    for (int dt = 0; dt < 4; ++dt)
#pragma unroll
      for (int nt = 0; nt < 2; ++nt)
        *(f32x4*)(osc + (wq * 32 + nt * 16 + ln) * 68 + dt * 16 + q4 * 4) =
            o_acc[dt][nt];
  }
  __syncthreads();

  if (wk == 0) {
    float rl[2];
#pragma unroll
    for (int nt = 0; nt < 2; ++nt)
      rl[nt] = 1.0f / (lsum[nt] + lsb[(wq * 2 + 1) * 32 + nt * 16 + ln]);
    // combine partials, rescale, drop O^T into LDS as [q][d] bf16
#pragma unroll
    for (int dt = 0; dt < 4; ++dt)
#pragma unroll
      for (int nt = 0; nt < 2; ++nt) {
        f32x4 part = *(const f32x4*)(osc + (wq * 32 + nt * 16 + ln) * 68 +
                                     dt * 16 + q4 * 4);
        f32x4 o = o_acc[dt][nt] + part;
        ushort4 pk4;
        pk4.x = f2bf(o[0] * rl[nt]); pk4.y = f2bf(o[1] * rl[nt]);
        pk4.z = f2bf(o[2] * rl[nt]); pk4.w = f2bf(o[3] * rl[nt]);
        *(ushort4*)(obuf + (wq * 32 + nt * 16 + ln) * 72 + dt * 16 + q4 * 4) = pk4;
      }
    asm volatile("s_waitcnt lgkmcnt(0)" ::: "memory");  // wave-local W->R fence
    // row read-out: 4 passes x (8 rows x 8 chunks) per wave
#pragma unroll
    for (int it = 0; it < 4; ++it) {
      int rr = it * 8 + (lane >> 3);
      int ch = lane & 7;
      bf16x8 rowv = *(const bf16x8*)(obuf + (wq * 32 + rr) * 72 + ch * 8);
      int tok = qt * 64 + wq * 32 + rr;
      *(bf16x8*)(outp + (bh_tok + tok) * 1024 + baseQ + ch * 8) = rowv;
    }
  }
}

// ------------------------------------------------------------------ LayerNorm rows
// one wave per row, 4 rows/block, shuffle-only reduction (no barrier).
__global__ __launch_bounds__(256) void ln_k(const float* __restrict__ res,
                                            const float* __restrict__ gamma,
                                            const float* __restrict__ beta,
                                            float* __restrict__ out) {
  int w = threadIdx.x >> 6, lane = threadIdx.x & 63;
  int row = blockIdx.x * 4 + w;
  const float* r = res + (size_t)row * DIMC;
  float4 v[4];
  float s = 0.f, ss = 0.f;
#pragma unroll
  for (int p = 0; p < 4; ++p) {
    v[p] = *(const float4*)(r + (p * 64 + lane) * 4);
    s += v[p].x + v[p].y + v[p].z + v[p].w;
    ss += v[p].x * v[p].x + v[p].y * v[p].y + v[p].z * v[p].z + v[p].w * v[p].w;
  }
#pragma unroll
  for (int off = 1; off < 64; off <<= 1) {
    s += __shfl_xor(s, off);
    ss += __shfl_xor(ss, off);
  }
  float mean = s * (1.0f / DIMC);
  float var = ss * (1.0f / DIMC) - mean * mean;
  float inv = rsqrtf(var + 1e-5f);
#pragma unroll
  for (int p = 0; p < 4; ++p) {
    int c = (p * 64 + lane) * 4;
    float4 g = *(const float4*)(gamma + c);
    float4 bt = *(const float4*)(beta + c);
    float4 o;
    o.x = (v[p].x - mean) * inv * g.x + bt.x;
    o.y = (v[p].y - mean) * inv * g.y + bt.y;
    o.z = (v[p].z - mean) * inv * g.z + bt.z;
    o.w = (v[p].w - mean) * inv * g.w + bt.w;
    *(float4*)(out + (size_t)row * DIMC + c) = o;
  }
}

extern "C" void kernel_launch(void* const* d_in, const int* in_sizes, int n_in,
                              void* d_out, int out_size, void* d_ws, size_t ws_size,
                              hipStream_t stream) {
  const float* x = (const float*)d_in[0];
  const float* w_qkv = (const float*)d_in[1];
  const float* w_out = (const float*)d_in[2];
  const float* b_out = (const float*)d_in[3];
  const float* gamma = (const float*)d_in[4];
  const float* beta = (const float*)d_in[5];
  float* outp = (float*)d_out;
  char* ws = (char*)d_ws;

  // ws layout (38 MB), aliasing by liveness (ORDER-SENSITIVE):
  //   [0,8M):   xb (bf16 x)         -> attnout after GEMM1
  //   [8,14M):  wqkvT               -> woutT ONLY after GEMM1 (R9/R11 bug)
  //   [14,30M): qk (bf16 4096x2048) -> res (f32 16MB) after attn
  //   [30,38M): vt (bf16 32x64x2048, V pre-transposed)
  u16* xb = (u16*)(ws);
  u16* wqkvT = (u16*)(ws + ((size_t)8 << 20));
  u16* qk = (u16*)(ws + ((size_t)14 << 20));
  u16* vt = (u16*)(ws + ((size_t)30 << 20));
  u16* attnout = (u16*)(ws);
  u16* woutT = (u16*)(ws + ((size_t)8 << 20));
  float* res = (float*)(ws + ((size_t)14 << 20));

  prep_k<<<7168, 256, 0, stream>>>(x, w_qkv, xb, wqkvT);
  gemm_bt<2, 128><<<dim3(24, 32), 256, 0, stream>>>(xb, wqkvT, qk, nullptr,
                                                    nullptr, nullptr, vt,
                                                    BLM, 3072, 1024);
  transpose_cast_k<<<dim3(32, 32), 256, 0, stream>>>(w_out, woutT, 1024, 1024);
  attn_fused<<<1024, 256, 0, stream>>>(qk, vt, attnout);
  gemm_bt<1, 64><<<dim3(8, 64), 256, 0, stream>>>(attnout, woutT, nullptr, res,
                                                  b_out, x, nullptr,
                                                  BLM, 1024, 1024);
  ln_k<<<1024, 256, 0, stream>>>(res, gamma, beta, outp);
}

// Round 4
// 195.823 us; speedup vs baseline: 1.0528x; 1.0033x over previous
//
#include <hip/hip_runtime.h>
#include <hip/hip_bf16.h>
#include <stdint.h>

// Problem constants (fixed-shape problem)
#define HEADS 16
#define HDIM  64
#define DIMC  1024
#define INNER 1024
#define LSEQ  2048
#define BLM   4096   // B*L

typedef unsigned short u16;
typedef __attribute__((ext_vector_type(8))) short bf16x8;  // 8 bf16 = 4 VGPRs
typedef __attribute__((ext_vector_type(4))) float f32x4;
typedef __attribute__((ext_vector_type(2))) unsigned int uint2v;

__device__ __forceinline__ u16 f2bf(float f) {
  union { float f; uint32_t u; } v; v.f = f;
  uint32_t u = v.u;
  return (u16)((u + 0x7fffu + ((u >> 16) & 1u)) >> 16);  // RNE
}
__device__ __forceinline__ uint32_t pack_bf2(float a, float b) {
  float2 f2; f2.x = a; f2.y = b;
  __hip_bfloat162 t = __float22bfloat162_rn(f2);
  union { __hip_bfloat162 h; uint32_t u; } c; c.h = t; return c.u;
}
// raw quarter-rate HW exp2 — avoids OCML's precise-path polynomial
__device__ __forceinline__ float fast_exp2(float x) {
  float r; asm("v_exp_f32 %0, %1" : "=v"(r) : "v"(x)); return r;
}

// async global->LDS, 16B per lane; LDS dest = wave-uniform base + lane*16
__device__ __forceinline__ void load_lds16(const void* g, void* l) {
  __builtin_amdgcn_global_load_lds(
      (const __attribute__((address_space(1))) uint32_t*)g,
      (__attribute__((address_space(3))) uint32_t*)l, 16, 0, 0);
}

// --------------------------------------------------- fused prep (1 launch):
// blocks [0,4096): cast x f32->bf16
// blocks [4096,7168): transpose+cast w_qkv [1024][3072] -> [3072][1024]
// NOTE: w_out transpose is NOT fused here. woutT aliases wqkvT's ws region
// and may only be written AFTER gemm1 has consumed wqkvT — writing it in
// prep clobbered the Q-columns of wqkvT (the R9/R11 absmax-0.316 bug).
__global__ __launch_bounds__(256) void prep_k(const float* __restrict__ x,
                                              const float* __restrict__ w_qkv,
                                              u16* __restrict__ xb,
                                              u16* __restrict__ wqkvT) {
  __shared__ float tile[32][33];
  int bid = blockIdx.x;
  if (bid < 4096) {
    int i = (bid * 256 + threadIdx.x) * 4;
    float4 v = *(const float4*)(x + i);
    ushort4 o;
    o.x = f2bf(v.x); o.y = f2bf(v.y); o.z = f2bf(v.z); o.w = f2bf(v.w);
    *(ushort4*)(xb + i) = o;
    return;
  }
  int idx = bid - 4096;
  int bx = idx % 96, by = idx / 96;   // C=3072 -> 96 col-tiles, R=1024 -> 32 row-tiles
  int c0 = bx * 32, r0 = by * 32;
  int j = threadIdx.x & 31, i0 = threadIdx.x >> 5;
#pragma unroll
  for (int p = 0; p < 4; ++p) {
    int i = i0 + p * 8;
    tile[i][j] = w_qkv[(size_t)(r0 + i) * 3072 + (c0 + j)];
  }
  __syncthreads();
#pragma unroll
  for (int p = 0; p < 4; ++p) {
    int i = i0 + p * 8;
    wqkvT[(size_t)(c0 + i) * 1024 + (r0 + j)] = f2bf(tile[j][i]);
  }
}

// ------------------------------------------------- transpose+cast: [R][C]f32 -> [C][R]bf16
__global__ __launch_bounds__(256) void transpose_cast_k(const float* __restrict__ in,
                                                        u16* __restrict__ out,
                                                        int R, int C) {
  __shared__ float tile[32][33];
  int c0 = blockIdx.x * 32, r0 = blockIdx.y * 32;
  int j = threadIdx.x & 31, i0 = threadIdx.x >> 5;
#pragma unroll
  for (int p = 0; p < 4; ++p) {
    int i = i0 + p * 8;
    tile[i][j] = in[(size_t)(r0 + i) * C + (c0 + j)];
  }
  __syncthreads();
#pragma unroll
  for (int p = 0; p < 4; ++p) {
    int i = i0 + p * 8;
    out[(size_t)(c0 + i) * R + (r0 + j)] = f2bf(tile[j][i]);
  }
}

// ------------------------------------------------------------------ GEMM (B^T input)
// C[M][N] = A[M][K] @ Bt[N][K], bf16 in, fp32 accum. TMx128 tile, BK=64.
// EPI==1: store f32 (acc + bias[col] + resid[row][col]).
// EPI==2: QKV split: cols<2048 -> Cb (stride 2048, Q|K packed);
//         cols>=2048 are V -> transposed store into Vt[bh][d][l].
template <int EPI, int TM>
__global__ __launch_bounds__(256) void gemm_bt(const u16* __restrict__ A,
                                               const u16* __restrict__ Bt,
                                               u16* __restrict__ Cb,
                                               float* __restrict__ Cf,
                                               const float* __restrict__ bias,
                                               const float* __restrict__ resid,
                                               u16* __restrict__ Vt,
                                               int M, int N, int K) {
  constexpr int MI = TM / 32;  // A-frags per wave (wave m-extent = TM/2)
  __shared__ alignas(16) u16 As[TM * 64];
  __shared__ alignas(16) u16 Bs[128 * 64];
  const int tid = threadIdx.x;
  const int lane = tid & 63;
  const int w = tid >> 6;
  const int wm = w >> 1, wn = w & 1;
  const int m0 = blockIdx.y * TM, n0 = blockIdx.x * 128;
  const int ln = lane & 15, qq = lane >> 4;
  const f32x4 zero4 = {0.f, 0.f, 0.f, 0.f};

  f32x4 acc[MI][4];
#pragma unroll
  for (int i = 0; i < MI; ++i)
#pragma unroll
    for (int j = 0; j < 4; ++j) acc[i][j] = zero4;

  for (int kt = 0; kt < K; kt += 64) {
    __syncthreads();
    // rows of 64 bf16 = 8 chunks of 16B; dest chunk d holds global chunk
    // d ^ (r&7) so frag reads (chunk (ks*4+qq)^(r&7)) spread all banks.
#pragma unroll
    for (int p = 0; p < TM / 32; ++p) {
      int t = p * 256 + tid;
      int r = t >> 3;
      int cl = (t & 7) ^ (r & 7);
      load_lds16(A + (size_t)(m0 + r) * K + kt + cl * 8,
                 (char*)As + (p * 256 + w * 64) * 16);
    }
#pragma unroll
    for (int p = 0; p < 4; ++p) {
      int t = p * 256 + tid;
      int r = t >> 3;
      int cl = (t & 7) ^ (r & 7);
      load_lds16(Bt + (size_t)(n0 + r) * K + kt + cl * 8,
                 (char*)Bs + (p * 256 + w * 64) * 16);
    }
    __syncthreads();
#pragma unroll
    for (int ks = 0; ks < 2; ++ks) {
      bf16x8 af[MI], bfr[4];
#pragma unroll
      for (int i = 0; i < MI; ++i) {
        int ra = wm * (TM / 2) + i * 16 + ln;
        af[i] = *(const bf16x8*)(As + (ra * 8 + ((ks * 4 + qq) ^ (ra & 7))) * 8);
      }
#pragma unroll
      for (int j = 0; j < 4; ++j) {
        int rb = wn * 64 + j * 16 + ln;
        bfr[j] = *(const bf16x8*)(Bs + (rb * 8 + ((ks * 4 + qq) ^ (rb & 7))) * 8);
      }
#pragma unroll
      for (int i = 0; i < MI; ++i)
#pragma unroll
        for (int j = 0; j < 4; ++j)
          acc[i][j] = __builtin_amdgcn_mfma_f32_16x16x32_bf16(af[i], bfr[j],
                                                              acc[i][j], 0, 0, 0);
    }
  }

  // C/D layout (m89-verified): col = lane&15, row = (lane>>4)*4 + reg
#pragma unroll
  for (int i = 0; i < MI; ++i) {
#pragma unroll
    for (int j = 0; j < 4; ++j) {
      int col = n0 + wn * 64 + j * 16 + ln;
      if (EPI == 1) {
#pragma unroll
        for (int rr = 0; rr < 4; ++rr) {
          int row = m0 + wm * (TM / 2) + i * 16 + qq * 4 + rr;
          Cf[(size_t)row * N + col] =
              acc[i][j][rr] + bias[col] + resid[(size_t)row * N + col];
        }
      } else {  // EPI == 2
        if (col < 2048) {
#pragma unroll
          for (int rr = 0; rr < 4; ++rr) {
            int row = m0 + wm * (TM / 2) + i * 16 + qq * 4 + rr;
            Cb[(size_t)row * 2048 + col] = f2bf(acc[i][j][rr]);
          }
        } else {
          // V column: store transposed Vt[(b*16+h)*64+d][l], 4 consecutive l
          int dg = col - 2048;
          int hh = dg >> 6, dd = dg & 63;
          int l0 = (m0 & 2047) + wm * (TM / 2) + i * 16 + qq * 4;
          int bb = m0 >> 11;
          ushort4 pk;
          pk.x = f2bf(acc[i][j][0]); pk.y = f2bf(acc[i][j][1]);
          pk.z = f2bf(acc[i][j][2]); pk.w = f2bf(acc[i][j][3]);
          *(ushort4*)(Vt + (((size_t)bb * 16 + hh) * 64 + dd) * 2048 + l0) = pk;
        }
      }
    }
  }
}

// ------------------------------------------------------------------ flash attention (S^T form)
// R16 = R15 (square 32x32 per-wave tiles, spill-proof vmcnt(0)+barrier
// schedule) + in-register P: the C-layout -> B-frag redistribution is done
// with cvt_pk packs + permlane32_swap . permlane16_swap (derived vs CDNA4
// ISA group semantics; composition is invariant to swap-direction reading).
// Removes the per-iter P LDS round-trip (4 ds_writes + lgkmcnt(0) drain +
// 2 ds_reads = ~250-300cy of wave-local critical path, the R15 limiter:
// per-iter wall was ~4455cy vs ~400cy of issued work). LDS 40->32 KB.
__global__ __launch_bounds__(256) void attn_fused(const u16* __restrict__ qk,
                                                  const u16* __restrict__ vt,
                                                  u16* __restrict__ outp) {
  const int bh = blockIdx.x & 31;   // b*16+h  -> XCD group = bh%8 (R10 remap)
  const int qt = blockIdx.x >> 5;
  const int h = bh & 15;
  const int b = bh >> 4;
  const int tid = threadIdx.x;
  const int lane = tid & 63;
  const int w = tid >> 6;
  const int wq = w & 1;    // q-half   (32 q rows)
  const int wk = w >> 1;   // key-half (32 keys)
  const int ln = lane & 15, q4 = lane >> 4;
  const int l7 = ln & 7;
  const f32x4 zero4 = {0.f, 0.f, 0.f, 0.f};

  // [0,16K): K double-buffer [2][64key][64d]  (chunk-swizzled c^(row&7))
  // [16K,32K): V^T double-buffer [2][64d][64key]
  // epilogue reuses [0,27K): osc f32[2][32][68] | lsb f32[2][2][32] | obuf u16[2][32][72]
  __shared__ alignas(16) char smem[32768];
  u16* Ksb = (u16*)smem;
  u16* Vsb = (u16*)(smem + 16384);

  const size_t bh_tok = (size_t)b * LSEQ;
  const size_t vbase = ((size_t)b * 16 + h) * 64 * 2048;
  const int baseQ = h * HDIM;

  // ---- Q raw loads FIRST (their wait cannot stall the staging DMA)
  bf16x8 qraw[2][2];
#pragma unroll
  for (int nt = 0; nt < 2; ++nt) {
    int row = qt * 64 + wq * 32 + nt * 16 + ln;
    const u16* p = qk + (bh_tok + row) * 2048 + baseQ;
#pragma unroll
    for (int ks = 0; ks < 2; ++ks)
      qraw[nt][ks] = *(const bf16x8*)(p + q4 * 8 + 32 * ks);
  }

  // ---- stage tile 0 into buf 0 (4 global_load_lds per lane)
#pragma unroll
  for (int iss = 0; iss < 2; ++iss) {
    int idx = iss * 256 + tid;
    int row = idx >> 3, c = idx & 7;
    int cl = c ^ (row & 7);
    load_lds16(qk + (bh_tok + row) * 2048 + 1024 + baseQ + cl * 8,
               (char*)Ksb + (iss * 256 + w * 64) * 16);
    load_lds16(vt + vbase + (size_t)row * 2048 + cl * 8,
               (char*)Vsb + (iss * 256 + w * 64) * 16);
  }

  // ---- Q fragments (B-operand: n=ln, k=q4*8+j (+32*ks)), scaled by log2e/8
  const float qscale = 0.125f * 1.44269504088896340736f;
  bf16x8 qf[2][2];  // [nt][ks]
#pragma unroll
  for (int nt = 0; nt < 2; ++nt)
#pragma unroll
    for (int ks = 0; ks < 2; ++ks) {
      bf16x8 v = qraw[nt][ks];
      bf16x8 o;
#pragma unroll
      for (int jj = 0; jj < 8; ++jj) {
        union { uint32_t u; float f; } cv; cv.u = ((uint32_t)(u16)v[jj]) << 16;
        o[jj] = (short)f2bf(cv.f * qscale);
      }
      qf[nt][ks] = o;
    }

  float lsum[2] = {0.f, 0.f};  // per-lane partial row sums, per nt (q=16nt+ln)
  f32x4 o_acc[4][2];           // O^T partial: [dt: d=16dt+4q4+r][nt: q=16nt+ln]
#pragma unroll
  for (int dt = 0; dt < 4; ++dt) {
    o_acc[dt][0] = zero4;
    o_acc[dt][1] = zero4;
  }

  // tile 0 landed everywhere before anyone computes
  asm volatile("s_waitcnt vmcnt(0)" ::: "memory");
  __builtin_amdgcn_s_barrier();

  int cur = 0;
#pragma unroll 1
  for (int jt = 0; jt < 32; ++jt) {
    // issue prefetch of tile jt+1 into buf cur^1; DMA flies under compute
    if (jt < 31) {
      const int key0 = (jt + 1) * 64;
#pragma unroll
      for (int iss = 0; iss < 2; ++iss) {
        int idx = iss * 256 + tid;
        int row = idx >> 3, c = idx & 7;
        int cl = c ^ (row & 7);
        load_lds16(qk + (bh_tok + key0 + row) * 2048 + 1024 + baseQ + cl * 8,
                   (char*)Ksb + (cur ^ 1) * 8192 + (iss * 256 + w * 64) * 16);
        load_lds16(vt + vbase + (size_t)row * 2048 + key0 + cl * 8,
                   (char*)Vsb + (cur ^ 1) * 8192 + (iss * 256 + w * 64) * 16);
      }
    }

    const u16* Ks = Ksb + cur * 4096;
    const u16* Vs = Vsb + cur * 4096;

    // S^T[32key][32q] = K·Q^T : 2 kt x 2 nt, 2 ks over d (4 K-frag reads)
    f32x4 s_[2][2];
#pragma unroll
    for (int kt = 0; kt < 2; ++kt) { s_[kt][0] = zero4; s_[kt][1] = zero4; }
#pragma unroll
    for (int kt = 0; kt < 2; ++kt) {
      int row = wk * 32 + kt * 16 + ln;
#pragma unroll
      for (int ks = 0; ks < 2; ++ks) {
        bf16x8 kf = *(const bf16x8*)(Ks + (row * 8 + ((ks * 4 + q4) ^ l7)) * 8);
        s_[kt][0] = __builtin_amdgcn_mfma_f32_16x16x32_bf16(kf, qf[0][ks], s_[kt][0], 0, 0, 0);
        s_[kt][1] = __builtin_amdgcn_mfma_f32_16x16x32_bf16(kf, qf[1][ks], s_[kt][1], 0, 0, 0);
      }
    }

    // static softmax: P = 2^S, accumulate per-lane per-nt partial sums
#pragma unroll
    for (int kt = 0; kt < 2; ++kt)
#pragma unroll
      for (int nt = 0; nt < 2; ++nt)
#pragma unroll
        for (int r = 0; r < 4; ++r) {
          float p = fast_exp2(s_[kt][nt][r]);
          s_[kt][nt][r] = p;
          lsum[nt] += p;
        }

    // In-register P^T C->B redistribution. C-layout: lane(q4,ln) holds
    // key_local = kt*16+q4*4+r at q=nt*16+ln. Pack key-pairs:
    //   x0 = kt0 keys (4q4+0,1), x1 = kt0 (4q4+2,3)   [pair idx k0 = 2q4 / 2q4+1]
    //   y0 = kt1 (16+4q4+0,1),   y1 = kt1 (16+4q4+2,3) [k0 = 8+2q4 / 9+2q4]
    // B-frag word Wd at lane-group g' needs pair k0 = 4g'+d.
    // pl32swap(x,y): x'={x.g0,x.g1,y.g0,y.g1}, y'={x.g2,x.g3,y.g2,y.g3};
    // pl16swap(x',y'): x''={x.g0,x.g2,y.g0,y.g2}=W(even), y''=W(even+2).
    bf16x8 pfrag[2];
#pragma unroll
    for (int nt = 0; nt < 2; ++nt) {
      uint32_t x0 = pack_bf2(s_[0][nt][0], s_[0][nt][1]);
      uint32_t x1 = pack_bf2(s_[0][nt][2], s_[0][nt][3]);
      uint32_t y0 = pack_bf2(s_[1][nt][0], s_[1][nt][1]);
      uint32_t y1 = pack_bf2(s_[1][nt][2], s_[1][nt][3]);
      uint2v r0 = __builtin_amdgcn_permlane32_swap(x0, y0, false, false);
      uint2v r1 = __builtin_amdgcn_permlane32_swap(x1, y1, false, false);
      uint2v t0 = __builtin_amdgcn_permlane16_swap(r0[0], r0[1], false, false);
      uint2v t1 = __builtin_amdgcn_permlane16_swap(r1[0], r1[1], false, false);
      union { uint32_t u[4]; bf16x8 v; } pf;
      pf.u[0] = t0[0];  // W0: keys 8g'+0,1
      pf.u[1] = t1[0];  // W1: keys 8g'+2,3
      pf.u[2] = t0[1];  // W2: keys 8g'+4,5
      pf.u[3] = t1[1];  // W3: keys 8g'+6,7
      pfrag[nt] = pf.v;
    }

    // O^T[64d][32q] += V^T[d][wk-keys] · P^T[wk-keys][q]  (4 V-frag reads, k=32)
#pragma unroll
    for (int dt = 0; dt < 4; ++dt) {
      int row = dt * 16 + ln;
      bf16x8 va = *(const bf16x8*)(Vs + (row * 8 + ((wk * 4 + q4) ^ l7)) * 8);
      o_acc[dt][0] = __builtin_amdgcn_mfma_f32_16x16x32_bf16(va, pfrag[0], o_acc[dt][0], 0, 0, 0);
      o_acc[dt][1] = __builtin_amdgcn_mfma_f32_16x16x32_bf16(va, pfrag[1], o_acc[dt][1], 0, 0, 0);
    }

    // drain prefetch DMA (counts ALL vmem incl. any scratch -> spill-proof),
    // then one barrier: all waves done reading cur AND tile jt+1 landed.
    asm volatile("s_waitcnt vmcnt(0)" ::: "memory");
    __builtin_amdgcn_s_barrier();
    cur ^= 1;
  }

  // ---- epilogue: reduce lsum over lane groups (keys of this wave's half)
#pragma unroll
  for (int nt = 0; nt < 2; ++nt) {
    lsum[nt] += __shfl_xor(lsum[nt], 16);
    lsum[nt] += __shfl_xor(lsum[nt], 32);
  }

  float* osc = (float*)smem;              // [wq][32 q][68] f32 (17408 B)
  float* lsb = (float*)(smem + 17408);    // [wq][wk][32 q]   (512 B)
  u16* obuf = (u16*)(smem + 17920);       // [wq][32 q][72] u16 (9216 B)

  if (q4 == 0) {
    lsb[(wq * 2 + wk) * 32 + ln] = lsum[0];
    lsb[(wq * 2 + wk) * 32 + 16 + ln] = lsum[1];
  }
  if (wk == 1) {
#pragma unroll
    for (int dt = 0; dt < 4; ++dt)
#pragma unroll
      for (int nt = 0; nt < 2; ++nt)
        *(f32x4*)(osc + (wq * 32 + nt * 16 + ln) * 68 + dt * 16 + q4 * 4) =
            o_acc[dt][nt];
  }
  __syncthreads();

  if (wk == 0) {
    float rl[2];
#pragma unroll
    for (int nt = 0; nt < 2; ++nt)
      rl[nt] = 1.0f / (lsum[nt] + lsb[(wq * 2 + 1) * 32 + nt * 16 + ln]);
    // combine partials, rescale, drop O^T into LDS as [q][d] bf16
#pragma unroll
    for (int dt = 0; dt < 4; ++dt)
#pragma unroll
      for (int nt = 0; nt < 2; ++nt) {
        f32x4 part = *(const f32x4*)(osc + (wq * 32 + nt * 16 + ln) * 68 +
                                     dt * 16 + q4 * 4);
        f32x4 o = o_acc[dt][nt] + part;
        ushort4 pk4;
        pk4.x = f2bf(o[0] * rl[nt]); pk4.y = f2bf(o[1] * rl[nt]);
        pk4.z = f2bf(o[2] * rl[nt]); pk4.w = f2bf(o[3] * rl[nt]);
        *(ushort4*)(obuf + (wq * 32 + nt * 16 + ln) * 72 + dt * 16 + q4 * 4) = pk4;
      }
    asm volatile("s_waitcnt lgkmcnt(0)" ::: "memory");  // wave-local W->R fence
    // row read-out: 4 passes x (8 rows x 8 chunks) per wave
#pragma unroll
    for (int it = 0; it < 4; ++it) {
      int rr = it * 8 + (lane >> 3);
      int ch = lane & 7;
      bf16x8 rowv = *(const bf16x8*)(obuf + (wq * 32 + rr) * 72 + ch * 8);
      int tok = qt * 64 + wq * 32 + rr;
      *(bf16x8*)(outp + (bh_tok + tok) * 1024 + baseQ + ch * 8) = rowv;
    }
  }
}

// ------------------------------------------------------------------ LayerNorm rows
// one wave per row, 4 rows/block, shuffle-only reduction (no barrier).
__global__ __launch_bounds__(256) void ln_k(const float* __restrict__ res,
                                            const float* __restrict__ gamma,
                                            const float* __restrict__ beta,
                                            float* __restrict__ out) {
  int w = threadIdx.x >> 6, lane = threadIdx.x & 63;
  int row = blockIdx.x * 4 + w;
  const float* r = res + (size_t)row * DIMC;
  float4 v[4];
  float s = 0.f, ss = 0.f;
#pragma unroll
  for (int p = 0; p < 4; ++p) {
    v[p] = *(const float4*)(r + (p * 64 + lane) * 4);
    s += v[p].x + v[p].y + v[p].z + v[p].w;
    ss += v[p].x * v[p].x + v[p].y * v[p].y + v[p].z * v[p].z + v[p].w * v[p].w;
  }
#pragma unroll
  for (int off = 1; off < 64; off <<= 1) {
    s += __shfl_xor(s, off);
    ss += __shfl_xor(ss, off);
  }
  float mean = s * (1.0f / DIMC);
  float var = ss * (1.0f / DIMC) - mean * mean;
  float inv = rsqrtf(var + 1e-5f);
#pragma unroll
  for (int p = 0; p < 4; ++p) {
    int c = (p * 64 + lane) * 4;
    float4 g = *(const float4*)(gamma + c);
    float4 bt = *(const float4*)(beta + c);
    float4 o;
    o.x = (v[p].x - mean) * inv * g.x + bt.x;
    o.y = (v[p].y - mean) * inv * g.y + bt.y;
    o.z = (v[p].z - mean) * inv * g.z + bt.z;
    o.w = (v[p].w - mean) * inv * g.w + bt.w;
    *(float4*)(out + (size_t)row * DIMC + c) = o;
  }
}

extern "C" void kernel_launch(void* const* d_in, const int* in_sizes, int n_in,
                              void* d_out, int out_size, void* d_ws, size_t ws_size,
                              hipStream_t stream) {
  const float* x = (const float*)d_in[0];
  const float* w_qkv = (const float*)d_in[1];
  const float* w_out = (const float*)d_in[2];
  const float* b_out = (const float*)d_in[3];
  const float* gamma = (const float*)d_in[4];
  const float* beta = (const float*)d_in[5];
  float* outp = (float*)d_out;
  char* ws = (char*)d_ws;

  // ws layout (38 MB), aliasing by liveness (ORDER-SENSITIVE):
  //   [0,8M):   xb (bf16 x)         -> attnout after GEMM1
  //   [8,14M):  wqkvT               -> woutT ONLY after GEMM1 (R9/R11 bug)
  //   [14,30M): qk (bf16 4096x2048) -> res (f32 16MB) after attn
  //   [30,38M): vt (bf16 32x64x2048, V pre-transposed)
  u16* xb = (u16*)(ws);
  u16* wqkvT = (u16*)(ws + ((size_t)8 << 20));
  u16* qk = (u16*)(ws + ((size_t)14 << 20));
  u16* vt = (u16*)(ws + ((size_t)30 << 20));
  u16* attnout = (u16*)(ws);
  u16* woutT = (u16*)(ws + ((size_t)8 << 20));
  float* res = (float*)(ws + ((size_t)14 << 20));

  prep_k<<<7168, 256, 0, stream>>>(x, w_qkv, xb, wqkvT);
  gemm_bt<2, 128><<<dim3(24, 32), 256, 0, stream>>>(xb, wqkvT, qk, nullptr,
                                                    nullptr, nullptr, vt,
                                                    BLM, 3072, 1024);
  transpose_cast_k<<<dim3(32, 32), 256, 0, stream>>>(w_out, woutT, 1024, 1024);
  attn_fused<<<1024, 256, 0, stream>>>(qk, vt, attnout);
  gemm_bt<1, 64><<<dim3(8, 64), 256, 0, stream>>>(attnout, woutT, nullptr, res,
                                                  b_out, x, nullptr,
                                                  BLM, 1024, 1024);
  ln_k<<<1024, 256, 0, stream>>>(res, gamma, beta, outp);
}

// Round 5
// 193.847 us; speedup vs baseline: 1.0636x; 1.0102x over previous
//
#include <hip/hip_runtime.h>
#include <hip/hip_bf16.h>
#include <stdint.h>

// Problem constants (fixed-shape problem)
#define HEADS 16
#define HDIM  64
#define DIMC  1024
#define INNER 1024
#define LSEQ  2048
#define BLM   4096   // B*L

typedef unsigned short u16;
typedef __attribute__((ext_vector_type(8))) short bf16x8;  // 8 bf16 = 4 VGPRs
typedef __attribute__((ext_vector_type(4))) float f32x4;
typedef __attribute__((ext_vector_type(2))) unsigned int uint2v;

__device__ __forceinline__ u16 f2bf(float f) {
  union { float f; uint32_t u; } v; v.f = f;
  uint32_t u = v.u;
  return (u16)((u + 0x7fffu + ((u >> 16) & 1u)) >> 16);  // RNE
}
__device__ __forceinline__ uint32_t pack_bf2(float a, float b) {
  float2 f2; f2.x = a; f2.y = b;
  __hip_bfloat162 t = __float22bfloat162_rn(f2);
  union { __hip_bfloat162 h; uint32_t u; } c; c.h = t; return c.u;
}
// raw quarter-rate HW exp2 — avoids OCML's precise-path polynomial
__device__ __forceinline__ float fast_exp2(float x) {
  float r; asm("v_exp_f32 %0, %1" : "=v"(r) : "v"(x)); return r;
}

// async global->LDS, 16B per lane; LDS dest = wave-uniform base + lane*16
__device__ __forceinline__ void load_lds16(const void* g, void* l) {
  __builtin_amdgcn_global_load_lds(
      (const __attribute__((address_space(1))) uint32_t*)g,
      (__attribute__((address_space(3))) uint32_t*)l, 16, 0, 0);
}

// --------------------------------------------------- fused prep (1 launch):
// blocks [0,4096): cast x f32->bf16
// blocks [4096,7168): transpose+cast w_qkv [1024][3072] -> [3072][1024]
// NOTE: w_out transpose is NOT fused here. woutT aliases wqkvT's ws region
// and may only be written AFTER gemm1 has consumed wqkvT — writing it in
// prep clobbered the Q-columns of wqkvT (the R9/R11 absmax-0.316 bug).
__global__ __launch_bounds__(256) void prep_k(const float* __restrict__ x,
                                              const float* __restrict__ w_qkv,
                                              u16* __restrict__ xb,
                                              u16* __restrict__ wqkvT) {
  __shared__ float tile[32][33];
  int bid = blockIdx.x;
  if (bid < 4096) {
    int i = (bid * 256 + threadIdx.x) * 4;
    float4 v = *(const float4*)(x + i);
    ushort4 o;
    o.x = f2bf(v.x); o.y = f2bf(v.y); o.z = f2bf(v.z); o.w = f2bf(v.w);
    *(ushort4*)(xb + i) = o;
    return;
  }
  int idx = bid - 4096;
  int bx = idx % 96, by = idx / 96;   // C=3072 -> 96 col-tiles, R=1024 -> 32 row-tiles
  int c0 = bx * 32, r0 = by * 32;
  int j = threadIdx.x & 31, i0 = threadIdx.x >> 5;
#pragma unroll
  for (int p = 0; p < 4; ++p) {
    int i = i0 + p * 8;
    tile[i][j] = w_qkv[(size_t)(r0 + i) * 3072 + (c0 + j)];
  }
  __syncthreads();
#pragma unroll
  for (int p = 0; p < 4; ++p) {
    int i = i0 + p * 8;
    wqkvT[(size_t)(c0 + i) * 1024 + (r0 + j)] = f2bf(tile[j][i]);
  }
}

// ------------------------------------------------- transpose+cast: [R][C]f32 -> [C][R]bf16
__global__ __launch_bounds__(256) void transpose_cast_k(const float* __restrict__ in,
                                                        u16* __restrict__ out,
                                                        int R, int C) {
  __shared__ float tile[32][33];
  int c0 = blockIdx.x * 32, r0 = blockIdx.y * 32;
  int j = threadIdx.x & 31, i0 = threadIdx.x >> 5;
#pragma unroll
  for (int p = 0; p < 4; ++p) {
    int i = i0 + p * 8;
    tile[i][j] = in[(size_t)(r0 + i) * C + (c0 + j)];
  }
  __syncthreads();
#pragma unroll
  for (int p = 0; p < 4; ++p) {
    int i = i0 + p * 8;
    out[(size_t)(c0 + i) * R + (r0 + j)] = f2bf(tile[j][i]);
  }
}

// ------------------------------------------------------------------ GEMM (B^T input)
// C[M][N] = A[M][K] @ Bt[N][K], bf16 in, fp32 accum. TMx128 tile, BK=64.
// EPI==1: store f32 (acc + bias[col] + resid[row][col]).
// EPI==2: QKV split: cols<2048 -> Cb (stride 2048, Q|K packed);
//         cols>=2048 are V -> transposed store into Vt[bh][d][l].
template <int EPI, int TM>
__global__ __launch_bounds__(256) void gemm_bt(const u16* __restrict__ A,
                                               const u16* __restrict__ Bt,
                                               u16* __restrict__ Cb,
                                               float* __restrict__ Cf,
                                               const float* __restrict__ bias,
                                               const float* __restrict__ resid,
                                               u16* __restrict__ Vt,
                                               int M, int N, int K) {
  constexpr int MI = TM / 32;  // A-frags per wave (wave m-extent = TM/2)
  __shared__ alignas(16) u16 As[TM * 64];
  __shared__ alignas(16) u16 Bs[128 * 64];
  const int tid = threadIdx.x;
  const int lane = tid & 63;
  const int w = tid >> 6;
  const int wm = w >> 1, wn = w & 1;
  const int m0 = blockIdx.y * TM, n0 = blockIdx.x * 128;
  const int ln = lane & 15, qq = lane >> 4;
  const f32x4 zero4 = {0.f, 0.f, 0.f, 0.f};

  f32x4 acc[MI][4];
#pragma unroll
  for (int i = 0; i < MI; ++i)
#pragma unroll
    for (int j = 0; j < 4; ++j) acc[i][j] = zero4;

  for (int kt = 0; kt < K; kt += 64) {
    __syncthreads();
    // rows of 64 bf16 = 8 chunks of 16B; dest chunk d holds global chunk
    // d ^ (r&7) so frag reads (chunk (ks*4+qq)^(r&7)) spread all banks.
#pragma unroll
    for (int p = 0; p < TM / 32; ++p) {
      int t = p * 256 + tid;
      int r = t >> 3;
      int cl = (t & 7) ^ (r & 7);
      load_lds16(A + (size_t)(m0 + r) * K + kt + cl * 8,
                 (char*)As + (p * 256 + w * 64) * 16);
    }
#pragma unroll
    for (int p = 0; p < 4; ++p) {
      int t = p * 256 + tid;
      int r = t >> 3;
      int cl = (t & 7) ^ (r & 7);
      load_lds16(Bt + (size_t)(n0 + r) * K + kt + cl * 8,
                 (char*)Bs + (p * 256 + w * 64) * 16);
    }
    __syncthreads();
#pragma unroll
    for (int ks = 0; ks < 2; ++ks) {
      bf16x8 af[MI], bfr[4];
#pragma unroll
      for (int i = 0; i < MI; ++i) {
        int ra = wm * (TM / 2) + i * 16 + ln;
        af[i] = *(const bf16x8*)(As + (ra * 8 + ((ks * 4 + qq) ^ (ra & 7))) * 8);
      }
#pragma unroll
      for (int j = 0; j < 4; ++j) {
        int rb = wn * 64 + j * 16 + ln;
        bfr[j] = *(const bf16x8*)(Bs + (rb * 8 + ((ks * 4 + qq) ^ (rb & 7))) * 8);
      }
#pragma unroll
      for (int i = 0; i < MI; ++i)
#pragma unroll
        for (int j = 0; j < 4; ++j)
          acc[i][j] = __builtin_amdgcn_mfma_f32_16x16x32_bf16(af[i], bfr[j],
                                                              acc[i][j], 0, 0, 0);
    }
  }

  // C/D layout (m89-verified): col = lane&15, row = (lane>>4)*4 + reg
#pragma unroll
  for (int i = 0; i < MI; ++i) {
#pragma unroll
    for (int j = 0; j < 4; ++j) {
      int col = n0 + wn * 64 + j * 16 + ln;
      if (EPI == 1) {
#pragma unroll
        for (int rr = 0; rr < 4; ++rr) {
          int row = m0 + wm * (TM / 2) + i * 16 + qq * 4 + rr;
          Cf[(size_t)row * N + col] =
              acc[i][j][rr] + bias[col] + resid[(size_t)row * N + col];
        }
      } else {  // EPI == 2
        if (col < 2048) {
#pragma unroll
          for (int rr = 0; rr < 4; ++rr) {
            int row = m0 + wm * (TM / 2) + i * 16 + qq * 4 + rr;
            Cb[(size_t)row * 2048 + col] = f2bf(acc[i][j][rr]);
          }
        } else {
          // V column: store transposed Vt[(b*16+h)*64+d][l], 4 consecutive l
          int dg = col - 2048;
          int hh = dg >> 6, dd = dg & 63;
          int l0 = (m0 & 2047) + wm * (TM / 2) + i * 16 + qq * 4;
          int bb = m0 >> 11;
          ushort4 pk;
          pk.x = f2bf(acc[i][j][0]); pk.y = f2bf(acc[i][j][1]);
          pk.z = f2bf(acc[i][j][2]); pk.w = f2bf(acc[i][j][3]);
          *(ushort4*)(Vt + (((size_t)bb * 16 + hh) * 64 + dd) * 2048 + l0) = pk;
        }
      }
    }
  }
}

// ------------------------------------------------------------------ flash attention (S^T form)
// R17 = R16 (square 32x32 wave tiles, in-register P via permlane swaps)
// with the sync structure changed from drain-per-iter to counted vmcnt:
//   issue DMA(jt+1) -> vmcnt(4) (tile jt landed; jt+1 stays in flight)
//   -> barrier -> compute(jt) -> barrier.
// Tile jt+1's DMA now has a full iteration to land instead of draining
// inside its own iteration (R15/R16's vmcnt(0) was the critical path:
// two compute-side optimizations moved wall time by only ~1us each).
// Safe vs R14's counted-vmcnt bug: VGPR=60 measured, no cap, no spills ->
// the only loop vmem ops are the 4 DMA loads, so the count is exact.
// DMA source addressing hoisted to running pointers (+64*2048 / +64).
__global__ __launch_bounds__(256) void attn_fused(const u16* __restrict__ qk,
                                                  const u16* __restrict__ vt,
                                                  u16* __restrict__ outp) {
  const int bh = blockIdx.x & 31;   // b*16+h  -> XCD group = bh%8 (R10 remap)
  const int qt = blockIdx.x >> 5;
  const int h = bh & 15;
  const int b = bh >> 4;
  const int tid = threadIdx.x;
  const int lane = tid & 63;
  const int w = tid >> 6;
  const int wq = w & 1;    // q-half   (32 q rows)
  const int wk = w >> 1;   // key-half (32 keys)
  const int ln = lane & 15, q4 = lane >> 4;
  const int l7 = ln & 7;
  const f32x4 zero4 = {0.f, 0.f, 0.f, 0.f};

  // [0,16K): K double-buffer [2][64key][64d]  (chunk-swizzled c^(row&7))
  // [16K,32K): V^T double-buffer [2][64d][64key]
  // epilogue reuses [0,27K): osc f32[2][32][68] | lsb f32[2][2][32] | obuf u16[2][32][72]
  __shared__ alignas(16) char smem[32768];
  u16* Ksb = (u16*)smem;
  u16* Vsb = (u16*)(smem + 16384);

  const size_t bh_tok = (size_t)b * LSEQ;
  const size_t vbase = ((size_t)b * 16 + h) * 64 * 2048;
  const int baseQ = h * HDIM;

  // ---- Q raw loads FIRST (retired at qf conversion below, pre-loop)
  bf16x8 qraw[2][2];
#pragma unroll
  for (int nt = 0; nt < 2; ++nt) {
    int row = qt * 64 + wq * 32 + nt * 16 + ln;
    const u16* p = qk + (bh_tok + row) * 2048 + baseQ;
#pragma unroll
    for (int ks = 0; ks < 2; ++ks)
      qraw[nt][ks] = *(const bf16x8*)(p + q4 * 8 + 32 * ks);
  }

  // ---- per-thread DMA geometry (hoisted): row/chunk per iss slot
  int r0_ = tid >> 3, c0_ = (tid & 7) ^ (r0_ & 7);
  int r1_ = (256 + tid) >> 3, c1_ = ((256 + tid) & 7) ^ (r1_ & 7);
  const u16* kp0 = qk + (bh_tok + r0_) * 2048 + 1024 + baseQ + c0_ * 8;
  const u16* kp1 = qk + (bh_tok + r1_) * 2048 + 1024 + baseQ + c1_ * 8;
  const u16* vp0 = vt + vbase + (size_t)r0_ * 2048 + c0_ * 8;
  const u16* vp1 = vt + vbase + (size_t)r1_ * 2048 + c1_ * 8;
  char* kd0 = (char*)Ksb + (w * 64) * 16;
  char* kd1 = (char*)Ksb + (256 + w * 64) * 16;
  char* vd0 = (char*)Vsb + (w * 64) * 16;
  char* vd1 = (char*)Vsb + (256 + w * 64) * 16;

  // ---- stage tile 0 into buf 0
  load_lds16(kp0, kd0);
  load_lds16(vp0, vd0);
  load_lds16(kp1, kd1);
  load_lds16(vp1, vd1);
  kp0 += 64 * 2048; kp1 += 64 * 2048; vp0 += 64; vp1 += 64;

  // ---- Q fragments (B-operand: n=ln, k=q4*8+j (+32*ks)), scaled by log2e/8
  const float qscale = 0.125f * 1.44269504088896340736f;
  bf16x8 qf[2][2];  // [nt][ks]
#pragma unroll
  for (int nt = 0; nt < 2; ++nt)
#pragma unroll
    for (int ks = 0; ks < 2; ++ks) {
      bf16x8 v = qraw[nt][ks];
      bf16x8 o;
#pragma unroll
      for (int jj = 0; jj < 8; ++jj) {
        union { uint32_t u; float f; } cv; cv.u = ((uint32_t)(u16)v[jj]) << 16;
        o[jj] = (short)f2bf(cv.f * qscale);
      }
      qf[nt][ks] = o;
    }

  float lsum[2] = {0.f, 0.f};  // per-lane partial row sums, per nt (q=16nt+ln)
  f32x4 o_acc[4][2];           // O^T partial: [dt: d=16dt+4q4+r][nt: q=16nt+ln]
#pragma unroll
  for (int dt = 0; dt < 4; ++dt) {
    o_acc[dt][0] = zero4;
    o_acc[dt][1] = zero4;
  }

  int cur = 0;
  int dstoff = 8192;  // byte offset of the prefetch destination buffer
#pragma unroll 1
  for (int jt = 0; jt < 32; ++jt) {
    // issue prefetch of tile jt+1 into the other buffer; counted wait:
    // vmcnt(4) retires tile jt's 4 loads, leaves jt+1's 4 in flight.
    if (jt < 31) {
      load_lds16(kp0, kd0 + dstoff);
      load_lds16(vp0, vd0 + dstoff);
      load_lds16(kp1, kd1 + dstoff);
      load_lds16(vp1, vd1 + dstoff);
      kp0 += 64 * 2048; kp1 += 64 * 2048; vp0 += 64; vp1 += 64;
      asm volatile("s_waitcnt vmcnt(4)" ::: "memory");
    } else {
      asm volatile("s_waitcnt vmcnt(0)" ::: "memory");
    }
    __builtin_amdgcn_s_barrier();  // everyone's tile-jt loads landed

    const u16* Ks = Ksb + cur * 4096;
    const u16* Vs = Vsb + cur * 4096;

    // S^T[32key][32q] = K·Q^T : 2 kt x 2 nt, 2 ks over d (4 K-frag reads)
    f32x4 s_[2][2];
#pragma unroll
    for (int kt = 0; kt < 2; ++kt) { s_[kt][0] = zero4; s_[kt][1] = zero4; }
#pragma unroll
    for (int kt = 0; kt < 2; ++kt) {
      int row = wk * 32 + kt * 16 + ln;
#pragma unroll
      for (int ks = 0; ks < 2; ++ks) {
        bf16x8 kf = *(const bf16x8*)(Ks + (row * 8 + ((ks * 4 + q4) ^ l7)) * 8);
        s_[kt][0] = __builtin_amdgcn_mfma_f32_16x16x32_bf16(kf, qf[0][ks], s_[kt][0], 0, 0, 0);
        s_[kt][1] = __builtin_amdgcn_mfma_f32_16x16x32_bf16(kf, qf[1][ks], s_[kt][1], 0, 0, 0);
      }
    }

    // static softmax: P = 2^S, accumulate per-lane per-nt partial sums
#pragma unroll
    for (int kt = 0; kt < 2; ++kt)
#pragma unroll
      for (int nt = 0; nt < 2; ++nt)
#pragma unroll
        for (int r = 0; r < 4; ++r) {
          float p = fast_exp2(s_[kt][nt][r]);
          s_[kt][nt][r] = p;
          lsum[nt] += p;
        }

    // In-register P^T C->B redistribution (R16-verified):
    // pl16swap(pl32swap(x,y)) -> B-frag words; invariant to swap direction.
    bf16x8 pfrag[2];
#pragma unroll
    for (int nt = 0; nt < 2; ++nt) {
      uint32_t x0 = pack_bf2(s_[0][nt][0], s_[0][nt][1]);
      uint32_t x1 = pack_bf2(s_[0][nt][2], s_[0][nt][3]);
      uint32_t y0 = pack_bf2(s_[1][nt][0], s_[1][nt][1]);
      uint32_t y1 = pack_bf2(s_[1][nt][2], s_[1][nt][3]);
      uint2v r0 = __builtin_amdgcn_permlane32_swap(x0, y0, false, false);
      uint2v r1 = __builtin_amdgcn_permlane32_swap(x1, y1, false, false);
      uint2v t0 = __builtin_amdgcn_permlane16_swap(r0[0], r0[1], false, false);
      uint2v t1 = __builtin_amdgcn_permlane16_swap(r1[0], r1[1], false, false);
      union { uint32_t u[4]; bf16x8 v; } pf;
      pf.u[0] = t0[0];  // W0: keys 8g'+0,1
      pf.u[1] = t1[0];  // W1: keys 8g'+2,3
      pf.u[2] = t0[1];  // W2: keys 8g'+4,5
      pf.u[3] = t1[1];  // W3: keys 8g'+6,7
      pfrag[nt] = pf.v;
    }

    // O^T[64d][32q] += V^T[d][wk-keys] · P^T[wk-keys][q]  (4 V-frag reads, k=32)
#pragma unroll
    for (int dt = 0; dt < 4; ++dt) {
      int row = dt * 16 + ln;
      bf16x8 va = *(const bf16x8*)(Vs + (row * 8 + ((wk * 4 + q4) ^ l7)) * 8);
      o_acc[dt][0] = __builtin_amdgcn_mfma_f32_16x16x32_bf16(va, pfrag[0], o_acc[dt][0], 0, 0, 0);
      o_acc[dt][1] = __builtin_amdgcn_mfma_f32_16x16x32_bf16(va, pfrag[1], o_acc[dt][1], 0, 0, 0);
    }

    // all waves done reading buf[cur] -> next iter may DMA into it
    __builtin_amdgcn_s_barrier();
    cur ^= 1;
    dstoff ^= 8192;
  }

  // ---- epilogue: reduce lsum over lane groups (keys of this wave's half)
#pragma unroll
  for (int nt = 0; nt < 2; ++nt) {
    lsum[nt] += __shfl_xor(lsum[nt], 16);
    lsum[nt] += __shfl_xor(lsum[nt], 32);
  }

  float* osc = (float*)smem;              // [wq][32 q][68] f32 (17408 B)
  float* lsb = (float*)(smem + 17408);    // [wq][wk][32 q]   (512 B)
  u16* obuf = (u16*)(smem + 17920);       // [wq][32 q][72] u16 (9216 B)

  if (q4 == 0) {
    lsb[(wq * 2 + wk) * 32 + ln] = lsum[0];
    lsb[(wq * 2 + wk) * 32 + 16 + ln] = lsum[1];
  }
  if (wk == 1) {
#pragma unroll
    for (int dt = 0; dt < 4; ++dt)
#pragma unroll
      for (int nt = 0; nt < 2; ++nt)
        *(f32x4*)(osc + (wq * 32 + nt * 16 + ln) * 68 + dt * 16 + q4 * 4) =
            o_acc[dt][nt];
  }
  __syncthreads();

  if (wk == 0) {
    float rl[2];
#pragma unroll
    for (int nt = 0; nt < 2; ++nt)
      rl[nt] = 1.0f / (lsum[nt] + lsb[(wq * 2 + 1) * 32 + nt * 16 + ln]);
    // combine partials, rescale, drop O^T into LDS as [q][d] bf16
#pragma unroll
    for (int dt = 0; dt < 4; ++dt)
#pragma unroll
      for (int nt = 0; nt < 2; ++nt) {
        f32x4 part = *(const f32x4*)(osc + (wq * 32 + nt * 16 + ln) * 68 +
                                     dt * 16 + q4 * 4);
        f32x4 o = o_acc[dt][nt] + part;
        ushort4 pk4;
        pk4.x = f2bf(o[0] * rl[nt]); pk4.y = f2bf(o[1] * rl[nt]);
        pk4.z = f2bf(o[2] * rl[nt]); pk4.w = f2bf(o[3] * rl[nt]);
        *(ushort4*)(obuf + (wq * 32 + nt * 16 + ln) * 72 + dt * 16 + q4 * 4) = pk4;
      }
    asm volatile("s_waitcnt lgkmcnt(0)" ::: "memory");  // wave-local W->R fence
    // row read-out: 4 passes x (8 rows x 8 chunks) per wave
#pragma unroll
    for (int it = 0; it < 4; ++it) {
      int rr = it * 8 + (lane >> 3);
      int ch = lane & 7;
      bf16x8 rowv = *(const bf16x8*)(obuf + (wq * 32 + rr) * 72 + ch * 8);
      int tok = qt * 64 + wq * 32 + rr;
      *(bf16x8*)(outp + (bh_tok + tok) * 1024 + baseQ + ch * 8) = rowv;
    }
  }
}

// ------------------------------------------------------------------ LayerNorm rows
// one wave per row, 4 rows/block, shuffle-only reduction (no barrier).
__global__ __launch_bounds__(256) void ln_k(const float* __restrict__ res,
                                            const float* __restrict__ gamma,
                                            const float* __restrict__ beta,
                                            float* __restrict__ out) {
  int w = threadIdx.x >> 6, lane = threadIdx.x & 63;
  int row = blockIdx.x * 4 + w;
  const float* r = res + (size_t)row * DIMC;
  float4 v[4];
  float s = 0.f, ss = 0.f;
#pragma unroll
  for (int p = 0; p < 4; ++p) {
    v[p] = *(const float4*)(r + (p * 64 + lane) * 4);
    s += v[p].x + v[p].y + v[p].z + v[p].w;
    ss += v[p].x * v[p].x + v[p].y * v[p].y + v[p].z * v[p].z + v[p].w * v[p].w;
  }
#pragma unroll
  for (int off = 1; off < 64; off <<= 1) {
    s += __shfl_xor(s, off);
    ss += __shfl_xor(ss, off);
  }
  float mean = s * (1.0f / DIMC);
  float var = ss * (1.0f / DIMC) - mean * mean;
  float inv = rsqrtf(var + 1e-5f);
#pragma unroll
  for (int p = 0; p < 4; ++p) {
    int c = (p * 64 + lane) * 4;
    float4 g = *(const float4*)(gamma + c);
    float4 bt = *(const float4*)(beta + c);
    float4 o;
    o.x = (v[p].x - mean) * inv * g.x + bt.x;
    o.y = (v[p].y - mean) * inv * g.y + bt.y;
    o.z = (v[p].z - mean) * inv * g.z + bt.z;
    o.w = (v[p].w - mean) * inv * g.w + bt.w;
    *(float4*)(out + (size_t)row * DIMC + c) = o;
  }
}

extern "C" void kernel_launch(void* const* d_in, const int* in_sizes, int n_in,
                              void* d_out, int out_size, void* d_ws, size_t ws_size,
                              hipStream_t stream) {
  const float* x = (const float*)d_in[0];
  const float* w_qkv = (const float*)d_in[1];
  const float* w_out = (const float*)d_in[2];
  const float* b_out = (const float*)d_in[3];
  const float* gamma = (const float*)d_in[4];
  const float* beta = (const float*)d_in[5];
  float* outp = (float*)d_out;
  char* ws = (char*)d_ws;

  // ws layout (38 MB), aliasing by liveness (ORDER-SENSITIVE):
  //   [0,8M):   xb (bf16 x)         -> attnout after GEMM1
  //   [8,14M):  wqkvT               -> woutT ONLY after GEMM1 (R9/R11 bug)
  //   [14,30M): qk (bf16 4096x2048) -> res (f32 16MB) after attn
  //   [30,38M): vt (bf16 32x64x2048, V pre-transposed)
  u16* xb = (u16*)(ws);
  u16* wqkvT = (u16*)(ws + ((size_t)8 << 20));
  u16* qk = (u16*)(ws + ((size_t)14 << 20));
  u16* vt = (u16*)(ws + ((size_t)30 << 20));
  u16* attnout = (u16*)(ws);
  u16* woutT = (u16*)(ws + ((size_t)8 << 20));
  float* res = (float*)(ws + ((size_t)14 << 20));

  prep_k<<<7168, 256, 0, stream>>>(x, w_qkv, xb, wqkvT);
  gemm_bt<2, 128><<<dim3(24, 32), 256, 0, stream>>>(xb, wqkvT, qk, nullptr,
                                                    nullptr, nullptr, vt,
                                                    BLM, 3072, 1024);
  transpose_cast_k<<<dim3(32, 32), 256, 0, stream>>>(w_out, woutT, 1024, 1024);
  attn_fused<<<1024, 256, 0, stream>>>(qk, vt, attnout);
  gemm_bt<1, 64><<<dim3(8, 64), 256, 0, stream>>>(attnout, woutT, nullptr, res,
                                                  b_out, x, nullptr,
                                                  BLM, 1024, 1024);
  ln_k<<<1024, 256, 0, stream>>>(res, gamma, beta, outp);
}